// Round 2
// baseline (318.801 us; speedup 1.0000x reference)
//
#include <hip/hip_runtime.h>
#include <stdint.h>

// Causal SDPA B=4,H=16,S=2048,D=64 fp32. Flash-MFMA bf16, round 6.
// SINGLE fused kernel: convert_prep deleted. The 114.7us total-vs-sdpa gap
// (196.4 total, 81.7 sdpa) was the prep pass + inter-kernel serialization;
// fusion removes it under either hypothesis.
//   - K: staged fp32->bf16 in registers during staging (same pkbf, same
//     swizzled LDS slots as v4).
//   - V: transposed during staging write: each thread loads one key's 16
//     d-values (4x float4) and scatters 16 ds_write_b16 into the swizzled
//     [d][key] tile (<=2 lanes/bank-word: free per m136).
//   - Compute phase / P-LDS / epilogue: verbatim v4 (proven 81.7us sdpa;
//     v5's 32x32 in-register softmax REGRESSED: MfmaUtil 17.4->14.6,
//     bank conflicts 3.24M->4.33M, spill traffic +15MB -> reverted).

#define SLEN 2048
#define DHEAD 64
#define PADP 72

typedef short bf16x8 __attribute__((ext_vector_type(8)));
typedef float f32x4 __attribute__((ext_vector_type(4)));

__device__ __forceinline__ uint32_t pkbf(float hi, float lo) {
    uint32_t a = __builtin_bit_cast(uint32_t, lo) + 0x8000u;
    uint32_t b = __builtin_bit_cast(uint32_t, hi) + 0x8000u;
    return __builtin_amdgcn_perm(b, a, 0x07060302u);
}
__device__ __forceinline__ unsigned short f2bf(float f) {
    return (unsigned short)((__builtin_bit_cast(uint32_t, f) + 0x8000u) >> 16);
}
__device__ __forceinline__ int swz(int row, int g) {  // offset in shorts, 64x64 tile
    return row * 64 + ((g ^ (row & 7)) << 3);
}

__global__ __launch_bounds__(256, 4)
void sdpa_fused(const float* __restrict__ Qf, const float* __restrict__ Kf,
                const float* __restrict__ Vf, float* __restrict__ Og) {
    const int n = blockIdx.x;
    const int j = n >> 8, c = n & 255;
    const int head = c & 63;
    const int A  = (c >> 6) + 4 * j;   // 0..15
    const int Bq = 31 - A;             // 16..31

    const size_t hb = (size_t)head * SLEN * DHEAD;
    const float* Qh = Qf + hb;
    const float* Kh = Kf + hb;
    const float* Vh = Vf + hb;
    float* Oh = Og + hb;

    const int tid  = threadIdx.x;
    const int w    = tid >> 6, lane = tid & 63;
    const int cl   = lane & 15, quad = lane >> 4;

    __shared__ unsigned short Kl[64 * 64];       // 8192 B swizzled [key][d]
    __shared__ unsigned short Vt[64 * 64];       // 8192 B swizzled [d][key]
    __shared__ unsigned short Pl[4 * 32 * PADP]; // 18432 B per-wave P [q][key]

    // waves 0,1 -> tile A; waves 2,3 -> tile B (balanced: 33 units/block)
    const int qw = ((w < 2) ? A * 64 : Bq * 64) + (w & 1) * 32;
    unsigned short* Plw = Pl + w * 32 * PADP;

    // Q fragments from fp32 global (once per block)
    bf16x8 qf[2][2];
#pragma unroll
    for (int m = 0; m < 2; ++m)
#pragma unroll
        for (int h = 0; h < 2; ++h) {
            const float* src = Qh + (size_t)(qw + m * 16 + cl) * DHEAD + h * 32 + quad * 8;
            float4 a = *(const float4*)src;
            float4 b = *(const float4*)(src + 4);
            uint4 u;
            u.x = pkbf(a.y, a.x); u.y = pkbf(a.w, a.z);
            u.z = pkbf(b.y, b.x); u.w = pkbf(b.w, b.z);
            qf[m][h] = __builtin_bit_cast(bf16x8, u);
        }

    f32x4 o[2][4];
#pragma unroll
    for (int m = 0; m < 2; ++m)
#pragma unroll
        for (int d = 0; d < 4; ++d) o[m][d] = (f32x4){0.f, 0.f, 0.f, 0.f};
    float ls[2] = {0.f, 0.f};
    const float SCL = 0.18033688f;   // (1/8) * log2(e)

    // --- K staging (fp32): rows srow0 and srow0+32, 8 floats at col sg0*8 ---
    const int srow0 = tid >> 3, sg0 = tid & 7;
    const int srow1 = srow0 + 32;
    const int lo0 = swz(srow0, sg0), lo1 = swz(srow1, sg0);
    const size_t kF0 = (size_t)srow0 * DHEAD + sg0 * 8;
    const size_t kF1 = (size_t)srow1 * DHEAD + sg0 * 8;

    // --- V staging (fp32, transposed): thread owns key=tid&63, d-block tid>>6 ---
    const int vkey = tid & 63, vdb = tid >> 6;
    const int kg = vkey >> 3, ko = vkey & 7;
    const int vr0w = vdb * 16;                    // first d-row this thread writes
    const size_t vF = (size_t)vkey * DHEAD + vdb * 16;

    const int ntiles = Bq + 1;
    float4 ka, kb_, kc_, kd_;
    float4 va, vb_, vc_, vd_;
    ka  = *(const float4*)(Kh + kF0);
    kb_ = *(const float4*)(Kh + kF0 + 4);
    kc_ = *(const float4*)(Kh + kF1);
    kd_ = *(const float4*)(Kh + kF1 + 4);
    va  = *(const float4*)(Vh + vF);
    vb_ = *(const float4*)(Vh + vF + 4);
    vc_ = *(const float4*)(Vh + vF + 8);
    vd_ = *(const float4*)(Vh + vF + 12);

    for (int t = 0; t < ntiles; ++t) {
        const int k0 = t * 64;
        __syncthreads();                      // prior tile's readers done
        {   // K tile: pack fp32 -> bf16, same swizzled slots as v4
            uint4 u;
            u.x = pkbf(ka.y, ka.x);   u.y = pkbf(ka.w, ka.z);
            u.z = pkbf(kb_.y, kb_.x); u.w = pkbf(kb_.w, kb_.z);
            *(uint4*)(Kl + lo0) = u;
            u.x = pkbf(kc_.y, kc_.x); u.y = pkbf(kc_.w, kc_.z);
            u.z = pkbf(kd_.y, kd_.x); u.w = pkbf(kd_.w, kd_.z);
            *(uint4*)(Kl + lo1) = u;
        }
        {   // V tile: transpose scatter, row r = vr0w+rr (rr&7 swizzle), col vkey
#define VW(rr, val) Vt[(vr0w + (rr)) * 64 + (((kg) ^ ((rr) & 7)) << 3) + ko] = f2bf(val)
            VW(0,  va.x);  VW(1,  va.y);  VW(2,  va.z);  VW(3,  va.w);
            VW(4,  vb_.x); VW(5,  vb_.y); VW(6,  vb_.z); VW(7,  vb_.w);
            VW(8,  vc_.x); VW(9,  vc_.y); VW(10, vc_.z); VW(11, vc_.w);
            VW(12, vd_.x); VW(13, vd_.y); VW(14, vd_.z); VW(15, vd_.w);
#undef VW
        }
        __syncthreads();
        if (t + 1 < ntiles) {                 // prefetch next tile into regs
            const size_t adv = (size_t)(k0 + 64) * DHEAD;
            ka  = *(const float4*)(Kh + kF0 + adv);
            kb_ = *(const float4*)(Kh + kF0 + adv + 4);
            kc_ = *(const float4*)(Kh + kF1 + adv);
            kd_ = *(const float4*)(Kh + kF1 + adv + 4);
            va  = *(const float4*)(Vh + vF + adv);
            vb_ = *(const float4*)(Vh + vF + adv + 4);
            vc_ = *(const float4*)(Vh + vF + adv + 8);
            vd_ = *(const float4*)(Vh + vF + adv + 12);
        }
        if (k0 > qw + 31) continue;           // wave-uniform; barriers are at loop top
        const bool partial = (k0 + 63 > qw);

        // S^T = K Q^T ; exp ; packed P^T write
#pragma unroll
        for (int kk = 0; kk < 4; ++kk) {
            bf16x8 kb0 = __builtin_bit_cast(bf16x8, *(const uint4*)(Kl + swz(kk * 16 + cl, quad)));
            bf16x8 kb1 = __builtin_bit_cast(bf16x8, *(const uint4*)(Kl + swz(kk * 16 + cl, 4 + quad)));
            const int krel = kk * 16 + quad * 4;
#pragma unroll
            for (int qq = 0; qq < 2; ++qq) {
                f32x4 s = (f32x4){0.f, 0.f, 0.f, 0.f};
                s = __builtin_amdgcn_mfma_f32_16x16x32_bf16(kb0, qf[qq][0], s, 0, 0, 0);
                s = __builtin_amdgcn_mfma_f32_16x16x32_bf16(kb1, qf[qq][1], s, 0, 0, 0);
                float p0, p1v, p2, p3;
                if (partial) {
                    const int qrel = qw - k0 + qq * 16 + cl;
                    p0 = (krel + 0 <= qrel) ? __builtin_amdgcn_exp2f(s[0] * SCL) : 0.f;
                    p1v = (krel + 1 <= qrel) ? __builtin_amdgcn_exp2f(s[1] * SCL) : 0.f;
                    p2 = (krel + 2 <= qrel) ? __builtin_amdgcn_exp2f(s[2] * SCL) : 0.f;
                    p3 = (krel + 3 <= qrel) ? __builtin_amdgcn_exp2f(s[3] * SCL) : 0.f;
                } else {
                    p0 = __builtin_amdgcn_exp2f(s[0] * SCL);
                    p1v = __builtin_amdgcn_exp2f(s[1] * SCL);
                    p2 = __builtin_amdgcn_exp2f(s[2] * SCL);
                    p3 = __builtin_amdgcn_exp2f(s[3] * SCL);
                }
                ls[qq] += (p0 + p1v) + (p2 + p3);
                uint2 pw;
                pw.x = pkbf(p1v, p0);
                pw.y = pkbf(p3, p2);
                *(uint2*)(Plw + (qq * 16 + cl) * PADP + kk * 16 + quad * 4) = pw;
            }
        }

        // P A-frags (same-wave LDS round trip) + V^T B-frags ; O += P V
        bf16x8 pa[2][2];
#pragma unroll
        for (int m = 0; m < 2; ++m)
#pragma unroll
            for (int h = 0; h < 2; ++h)
                pa[m][h] = __builtin_bit_cast(bf16x8,
                    *(const uint4*)(Plw + (m * 16 + cl) * PADP + h * 32 + quad * 8));
#pragma unroll
        for (int dd = 0; dd < 4; ++dd) {
            bf16x8 vb0 = __builtin_bit_cast(bf16x8, *(const uint4*)(Vt + swz(dd * 16 + cl, quad)));
            bf16x8 vb1 = __builtin_bit_cast(bf16x8, *(const uint4*)(Vt + swz(dd * 16 + cl, 4 + quad)));
#pragma unroll
            for (int m = 0; m < 2; ++m) {
                o[m][dd] = __builtin_amdgcn_mfma_f32_16x16x32_bf16(pa[m][0], vb0, o[m][dd], 0, 0, 0);
                o[m][dd] = __builtin_amdgcn_mfma_f32_16x16x32_bf16(pa[m][1], vb1, o[m][dd], 0, 0, 0);
            }
        }
    }

    // row-sum: reduce across the 4 quads holding the same q (=cl)
#pragma unroll
    for (int qq = 0; qq < 2; ++qq) {
        float v = ls[qq];
        v += __shfl_xor(v, 16);
        v += __shfl_xor(v, 32);
        ls[qq] = v;
    }

    // normalize + store: O row q = qw + m*16 + quad*4 + r, col = dd*16 + cl
#pragma unroll
    for (int m = 0; m < 2; ++m)
#pragma unroll
        for (int r = 0; r < 4; ++r) {
            const float inv = 1.0f / __shfl(ls[m], quad * 4 + r);
#pragma unroll
            for (int dd = 0; dd < 4; ++dd)
                Oh[(size_t)(qw + m * 16 + quad * 4 + r) * DHEAD + dd * 16 + cl] = o[m][dd][r] * inv;
        }
}

extern "C" void kernel_launch(void* const* d_in, const int* in_sizes, int n_in,
                              void* d_out, int out_size, void* d_ws, size_t ws_size,
                              hipStream_t stream) {
    const float* Q = (const float*)d_in[0];
    const float* K = (const float*)d_in[1];
    const float* V = (const float*)d_in[2];
    float*       O = (float*)d_out;
    (void)d_ws; (void)ws_size;

    sdpa_fused<<<dim3(1024), dim3(256), 0, stream>>>(Q, K, V, O);
}